// Round 4
// baseline (370.203 us; speedup 1.0000x reference)
//
#include <hip/hip_runtime.h>
#include <cfloat>

// VQ quantizer: pure-hi fp16 MFMA scan + packed u32 top-2 (v_med3) + wave-
// parallel fp64 exact refine of near-ties.
//   scan dist' = cn + 256 - 2*dot_hi, dot_hi = sum qh*ch (single f16 product).
//   scan error e = 2*sum(q*r_c + r_q*c): rms ~2.4e-3, 13-sigma ~0.031 = E.
//   9-bit mask quant Q <= 0.03125 (d' < 1024 always). DELTA = 0.09375 >= 2E+Q
//   -> every potentially-wrong argmin (incl. packed ties) is flagged and
//   exactly re-decided in fp64 (dot expansion + fp64 codebook norms; the
//   per-row ||q||^2 constant cancels in argmin). dist' > 0 -> IEEE bits sort
//   as u32; low 9 mantissa bits carry the code index (tie -> smaller code).
// Structure (round-2 skeleton, fattened waves): 64 rows/wave, 256 rows/block.
// B-frags staged to LDS via global_load_lds, 16 KiB (2 tiles) per round,
// double-buffered, ONE barrier per round (its vmcnt drain lands the
// prefetch). cn in LDS. Refine + epilogue are per-wave, barrier-free.

#define DDIM 64
#define KCB  512
#define DELTA 0.09375f

typedef _Float16 f16x8 __attribute__((ext_vector_type(8)));
typedef float    f32x4 __attribute__((ext_vector_type(4)));

// ws layout (bytes)
#define WS_CN    0                         // float  cn[512]+256     [0, 2048)
#define WS_CN64  2048                      // double cn64[512]       [2048, 6144)
#define WS_FRAG  8192                      // 32 subs * 2 KiB hi-f16 [8192, 73728)
#define WS_CBT   73728                     // float  cbT[64][512]    [73728, 204800)

__device__ __forceinline__ unsigned umed3(unsigned a, unsigned b, unsigned c) {
    unsigned d;
    asm("v_med3_u32 %0, %1, %2, %3" : "=v"(d) : "v"(a), "v"(b), "v"(c));
    return d;
}

typedef const unsigned int __attribute__((address_space(1))) as1_uint;
typedef unsigned int __attribute__((address_space(3))) as3_uint;

__device__ __forceinline__ void gload16(const void* g, void* l) {
    __builtin_amdgcn_global_load_lds((as1_uint*)g, (as3_uint*)l, 16, 0, 0);
}

// ---------------- K_pre (64 blocks x 256) ----------------
__global__ void k_pre(const float* __restrict__ cb, char* __restrict__ ws) {
    int gid = blockIdx.x * 256 + threadIdx.x;        // 0..16383
    if (gid < 4096) {
        // hi f16 frags: 32 sub-tiles x 128 entries of 16 B
        int t    = gid >> 9;
        int h    = gid & 511;
        int lane = h & 63;
        int subkb = h >> 6;                 // sub*2+kb
        int sub  = subkb >> 1;
        int kb   = subkb & 1;
        int code = t * 64 + sub * 16 + (lane & 15);
        int d0   = kb * 32 + ((lane >> 4) & 3) * 8;
        const float* src = cb + (size_t)code * DDIM + d0;
        union { _Float16 hv[8]; float4 f4; } hi;
        #pragma unroll
        for (int j = 0; j < 8; ++j) hi.hv[j] = (_Float16)src[j];   // RTNE
        *(float4*)(ws + WS_FRAG + (size_t)t * 8192 + (size_t)h * 16) = hi.f4;
    } else if (gid < 4608) {
        // codebook norms (fp64 exact, fp32+256 for the scan)
        int code = gid - 4096;
        const float4* c4 = (const float4*)(cb + (size_t)code * DDIM);
        double s0 = 0.0, s1 = 0.0, s2 = 0.0, s3 = 0.0;
        #pragma unroll
        for (int j = 0; j < 16; ++j) {
            float4 v = c4[j];
            s0 = fma((double)v.x, (double)v.x, s0);
            s1 = fma((double)v.y, (double)v.y, s1);
            s2 = fma((double)v.z, (double)v.z, s2);
            s3 = fma((double)v.w, (double)v.w, s3);
        }
        double s = (s0 + s1) + (s2 + s3);
        ((float*)(ws + WS_CN))[code] = (float)s + 256.0f;
        ((double*)(ws + WS_CN64))[code] = s;
    } else if (gid >= 8192) {
        // transposed fp32 codebook for the coalesced refine
        int idx = gid - 8192;               // 0..8191
        int d  = idx >> 7;                  // 0..63
        int k4 = (idx & 127) * 4;           // 0..508
        float tmp[4];
        #pragma unroll
        for (int j = 0; j < 4; ++j) tmp[j] = cb[(size_t)(k4 + j) * DDIM + d];
        float* row = (float*)(ws + WS_CBT) + d * KCB + k4;
        *(float4*)row = make_float4(tmp[0], tmp[1], tmp[2], tmp[3]);
    }
}

// ---------------- K1 ----------------
__global__ __launch_bounds__(256, 4) void k1(
    const float* __restrict__ ze, const float* __restrict__ cb,
    float* __restrict__ out, const char* __restrict__ ws)
{
    __shared__ f16x8 s_frag[2][1024];       // 2 x 16 KiB round buffers
    __shared__ float s_cn[KCB];             // 2 KiB (cn+256)
    __shared__ int   s_bidx[4][64];         // per-wave private slices

    const int tid  = threadIdx.x;
    const int wave = tid >> 6;
    const int lane = tid & 63;
    const int quad = (lane >> 4) & 3;
    const int qb_wave = blockIdx.x * 256 + wave * 64;

    const char* fragg = ws + WS_FRAG;

    // issue round 0 (tiles 0,1 = 16 KiB) -> buffer 0
    #pragma unroll
    for (int j = 0; j < 4; ++j)
        gload16(fragg + j * 4096 + wave * 1024 + lane * 16,
                (char*)s_frag[0] + j * 4096 + wave * 1024);

    for (int i = tid; i < KCB; i += 256) s_cn[i] = ((const float*)(ws + WS_CN))[i];

    // A fragments: 4 M-tiles x 2 k-blocks, hi fp16 only (RTNE)
    union { f16x8 v; _Float16 h[8]; } qh[4][2];
    #pragma unroll
    for (int m = 0; m < 4; ++m) {
        int row = qb_wave + m * 16 + (lane & 15);
        #pragma unroll
        for (int kb = 0; kb < 2; ++kb) {
            int d0 = kb * 32 + quad * 8;
            const float4* qs = (const float4*)(ze + (size_t)row * DDIM + d0);
            float4 a = qs[0], b = qs[1];
            float f[8] = {a.x,a.y,a.z,a.w,b.x,b.y,b.z,b.w};
            #pragma unroll
            for (int j = 0; j < 8; ++j) qh[m][kb].h[j] = (_Float16)f[j];
        }
    }

    unsigned b2[4][4], s2[4][4];
    #pragma unroll
    for (int m = 0; m < 4; ++m)
        #pragma unroll
        for (int r = 0; r < 4; ++r) { b2[m][r] = 0xFFFFFFFFu; s2[m][r] = 0xFFFFFFFFu; }

    __syncthreads();                        // round 0 + s_cn ready

    for (int rr = 0; rr < 4; ++rr) {
        int cur = rr & 1;
        if (rr < 3) {                       // prefetch round rr+1 -> other buffer
            const char* src = fragg + (size_t)(rr + 1) * 16384;
            char* dst = (char*)s_frag[cur ^ 1];
            #pragma unroll
            for (int j = 0; j < 4; ++j)
                gload16(src + j * 4096 + wave * 1024 + lane * 16,
                        dst + j * 4096 + wave * 1024);
        }
        #pragma unroll
        for (int ss = 0; ss < 8; ++ss) {
            f16x8 bh0 = s_frag[cur][ss * 128 + lane];
            f16x8 bh1 = s_frag[cur][ss * 128 + 64 + lane];
            f32x4 aa[4];
            #pragma unroll
            for (int m = 0; m < 4; ++m) aa[m] = (f32x4){0,0,0,0};
            #pragma unroll
            for (int m = 0; m < 4; ++m)
                aa[m] = __builtin_amdgcn_mfma_f32_16x16x32_f16(qh[m][0].v, bh0, aa[m], 0, 0, 0);
            #pragma unroll
            for (int m = 0; m < 4; ++m)
                aa[m] = __builtin_amdgcn_mfma_f32_16x16x32_f16(qh[m][1].v, bh1, aa[m], 0, 0, 0);

            int s = rr * 8 + ss;
            unsigned code = (unsigned)(s * 16) + (unsigned)(lane & 15);
            float cnv = s_cn[s * 16 + (lane & 15)];
            #pragma unroll
            for (int m = 0; m < 4; ++m) {
                #pragma unroll
                for (int r = 0; r < 4; ++r) {
                    float d0 = fmaf(aa[m][r], -2.0f, cnv);
                    unsigned u0 = (__float_as_uint(d0) & 0xFFFFFE00u) | code;
                    s2[m][r] = umed3(b2[m][r], s2[m][r], u0);
                    b2[m][r] = min(b2[m][r], u0);
                }
            }
        }
        __syncthreads();                    // drains vmcnt: round rr+1 landed;
                                            // all waves done reading buf cur
    }

    // ---- cross-lane top-2 merge + ballot flag collection (wave-uniform) ----
    unsigned long long rowmask = 0;
    #pragma unroll
    for (int m = 0; m < 4; ++m) {
        #pragma unroll
        for (int r = 0; r < 4; ++r) {
            unsigned b = b2[m][r], s = s2[m][r];
            #pragma unroll
            for (int mask = 1; mask < 16; mask <<= 1) {
                unsigned ob = __shfl_xor((int)b, mask);
                unsigned os = __shfl_xor((int)s, mask);
                s = min(min(s, os), max(b, ob));
                b = min(b, ob);
            }
            bool flag = false;
            if ((lane & 15) == 0) {
                int lrow = m * 16 + quad * 4 + r;
                s_bidx[wave][lrow] = (int)(b & 511u);
                float fb_ = __uint_as_float(b & 0xFFFFFE00u);
                float fs_ = __uint_as_float(s & 0xFFFFFE00u);
                flag = (fs_ - fb_ <= DELTA);
            }
            unsigned long long bal = __ballot(flag);   // bits at 0/16/32/48
            rowmask |= (( bal        & 1ull) << (m * 16 + 0  + r))
                     | (((bal >> 16) & 1ull) << (m * 16 + 4  + r))
                     | (((bal >> 32) & 1ull) << (m * 16 + 8  + r))
                     | (((bal >> 48) & 1ull) << (m * 16 + 12 + r));
        }
    }

    // ---- per-wave fp64 exact refine (wave-uniform rowmask loop) ----
    const float*  cbT  = (const float*)(ws + WS_CBT);
    const double* cn64 = (const double*)(ws + WS_CN64);
    while (rowmask) {
        int lrow = (int)__builtin_ctzll(rowmask);
        rowmask &= rowmask - 1;
        int q = qb_wave + lrow;
        float qv = ze[(size_t)q * DDIM + lane];          // lane d holds q[d]
        double acc[8] = {0,0,0,0,0,0,0,0};               // codes lane*8+j
        #pragma unroll 8
        for (int d = 0; d < DDIM; ++d) {
            double qd = (double)__shfl(qv, d);
            const float4* c4 = (const float4*)(cbT + d * KCB + lane * 8);
            float4 x = c4[0], y = c4[1];
            acc[0] = fma((double)x.x, qd, acc[0]);
            acc[1] = fma((double)x.y, qd, acc[1]);
            acc[2] = fma((double)x.z, qd, acc[2]);
            acc[3] = fma((double)x.w, qd, acc[3]);
            acc[4] = fma((double)y.x, qd, acc[4]);
            acc[5] = fma((double)y.y, qd, acc[5]);
            acc[6] = fma((double)y.z, qd, acc[6]);
            acc[7] = fma((double)y.w, qd, acc[7]);
        }
        double v = DBL_MAX; int ki = 0;
        #pragma unroll
        for (int j = 0; j < 8; ++j) {                    // j asc -> smaller code wins ties
            int k = lane * 8 + j;
            double dj = fma(-2.0, acc[j], cn64[k]);      // d' - ||q||^2
            if (dj < v) { v = dj; ki = k; }
        }
        #pragma unroll
        for (int off = 1; off < 64; off <<= 1) {
            double ov = __shfl_xor(v, off);
            int    oi = __shfl_xor(ki, off);
            if (ov < v || (ov == v && oi < ki)) { v = ov; ki = oi; }
        }
        if (lane == 0) s_bidx[wave][lrow] = ki;
    }

    // ---- per-wave output: direct gather cb[bidx] -> out ----
    const float4* cb4 = (const float4*)cb;
    float4* o4 = (float4*)out + (size_t)qb_wave * 16;
    #pragma unroll
    for (int i = 0; i < 16; ++i) {
        int cc  = i * 64 + lane;            // 0..1023
        int row = cc >> 4;                  // 0..63
        int sg  = cc & 15;
        int bi  = s_bidx[wave][row];
        o4[(size_t)row * 16 + sg] = cb4[(size_t)bi * 16 + sg];
    }
}

extern "C" void kernel_launch(void* const* d_in, const int* in_sizes, int n_in,
                              void* d_out, int out_size, void* d_ws, size_t ws_size,
                              hipStream_t stream) {
    const float* ze = (const float*)d_in[0];
    const float* cb = (const float*)d_in[1];
    float* out = (float*)d_out;
    char* ws = (char*)d_ws;

    const int nq = in_sizes[0] / DDIM;                 // 524288
    k_pre<<<64, 256, 0, stream>>>(cb, ws);
    k1<<<nq / 256, 256, 0, stream>>>(ze, cb, out, ws);
}

// Round 5
// 334.645 us; speedup vs baseline: 1.1063x; 1.1063x over previous
//
#include <hip/hip_runtime.h>
#include <cfloat>

// VQ quantizer: pure-hi fp16 MFMA scan + packed u32 top-2 (v_med3) + wave-
// parallel fp64 exact refine of near-ties.
//   scan dist' = cn + 256 - 2*dot_hi, dot_hi = sum qh*ch (single f16 product).
//   scan error e = 2*sum(q*r_c + r_q*c): rms ~2.4e-3, 13-sigma ~0.031 = E.
//   9-bit mask quant Q <= 0.03125 (d' < 1024 always). DELTA = 0.09375 >= 2E+Q
//   -> every potentially-wrong argmin (incl. packed ties) is flagged and
//   exactly re-decided in fp64 (dot expansion + fp64 codebook norms; the
//   per-row ||q||^2 constant cancels in argmin). dist' > 0 -> IEEE bits sort
//   as u32; low 9 mantissa bits carry the code index (tie -> smaller code).
// Pipeline (T4 counted-vmcnt): 3 x 8 KiB LDS ring, global_load_lds issued
// 2 tiles ahead; per tile ONE raw s_barrier preceded by s_waitcnt vmcnt(2)
// (never 0 until the last tile) so prefetches stay in flight across
// barriers. Whole-tile B-frag register preload (8 ds_read_b128 before the
// 16 MFMAs). Merge/refine/epilogue are per-wave, barrier-free.

#define DDIM 64
#define KCB  512
#define DELTA 0.09375f

typedef _Float16 f16x8 __attribute__((ext_vector_type(8)));
typedef float    f32x4 __attribute__((ext_vector_type(4)));

// ws layout (bytes)
#define WS_CN    0                         // float  cn[512]+256     [0, 2048)
#define WS_CN64  2048                      // double cn64[512]       [2048, 6144)
#define WS_FRAG  8192                      // 8 tiles * 8 KiB hi-f16 [8192, 73728)
#define WS_CBT   73728                     // float  cbT[64][512]    [73728, 204800)

__device__ __forceinline__ unsigned umed3(unsigned a, unsigned b, unsigned c) {
    unsigned d;
    asm("v_med3_u32 %0, %1, %2, %3" : "=v"(d) : "v"(a), "v"(b), "v"(c));
    return d;
}

typedef const unsigned int __attribute__((address_space(1))) as1_uint;
typedef unsigned int __attribute__((address_space(3))) as3_uint;

__device__ __forceinline__ void gload16(const void* g, void* l) {
    __builtin_amdgcn_global_load_lds((as1_uint*)g, (as3_uint*)l, 16, 0, 0);
}

// ---------------- K_pre (64 blocks x 256) ----------------
__global__ void k_pre(const float* __restrict__ cb, char* __restrict__ ws) {
    int gid = blockIdx.x * 256 + threadIdx.x;        // 0..16383
    if (gid < 4096) {
        // hi f16 frags: 8 tiles x 512 entries of 16 B
        int t    = gid >> 9;
        int h    = gid & 511;
        int lane = h & 63;
        int subkb = h >> 6;                 // sub*2+kb
        int sub  = subkb >> 1;
        int kb   = subkb & 1;
        int code = t * 64 + sub * 16 + (lane & 15);
        int d0   = kb * 32 + ((lane >> 4) & 3) * 8;
        const float* src = cb + (size_t)code * DDIM + d0;
        union { _Float16 hv[8]; float4 f4; } hi;
        #pragma unroll
        for (int j = 0; j < 8; ++j) hi.hv[j] = (_Float16)src[j];   // RTNE
        *(float4*)(ws + WS_FRAG + (size_t)t * 8192 + (size_t)h * 16) = hi.f4;
    } else if (gid < 4608) {
        // codebook norms (fp64 exact, fp32+256 for the scan)
        int code = gid - 4096;
        const float4* c4 = (const float4*)(cb + (size_t)code * DDIM);
        double s0 = 0.0, s1 = 0.0, s2 = 0.0, s3 = 0.0;
        #pragma unroll
        for (int j = 0; j < 16; ++j) {
            float4 v = c4[j];
            s0 = fma((double)v.x, (double)v.x, s0);
            s1 = fma((double)v.y, (double)v.y, s1);
            s2 = fma((double)v.z, (double)v.z, s2);
            s3 = fma((double)v.w, (double)v.w, s3);
        }
        double s = (s0 + s1) + (s2 + s3);
        ((float*)(ws + WS_CN))[code] = (float)s + 256.0f;
        ((double*)(ws + WS_CN64))[code] = s;
    } else if (gid >= 8192) {
        // transposed fp32 codebook for the coalesced refine
        int idx = gid - 8192;               // 0..8191
        int d  = idx >> 7;                  // 0..63
        int k4 = (idx & 127) * 4;           // 0..508
        float tmp[4];
        #pragma unroll
        for (int j = 0; j < 4; ++j) tmp[j] = cb[(size_t)(k4 + j) * DDIM + d];
        float* row = (float*)(ws + WS_CBT) + d * KCB + k4;
        *(float4*)row = make_float4(tmp[0], tmp[1], tmp[2], tmp[3]);
    }
}

// ---------------- K1 ----------------
__global__ __launch_bounds__(256, 4) void k1(
    const float* __restrict__ ze, const float* __restrict__ cb,
    float* __restrict__ out, const char* __restrict__ ws)
{
    __shared__ f16x8 s_frag[3][512];        // 3 x 8 KiB ring buffers
    __shared__ float s_cn[KCB];             // 2 KiB (cn+256)
    __shared__ int   s_bidx[4][32];         // per-wave private slices

    const int tid  = threadIdx.x;
    const int wave = tid >> 6;
    const int lane = tid & 63;
    const int quad = (lane >> 4) & 3;
    const int qb_wave = blockIdx.x * 128 + wave * 32;

    const char* fragg = ws + WS_FRAG;

    // (1) A-fragment global loads + convert (consumed before gloads issue,
    //     so their waitcnts never drain the prefetch queue)
    union { f16x8 v; _Float16 h[8]; } qh[2][2];
    #pragma unroll
    for (int m = 0; m < 2; ++m) {
        int row = qb_wave + m * 16 + (lane & 15);
        #pragma unroll
        for (int kb = 0; kb < 2; ++kb) {
            int d0 = kb * 32 + quad * 8;
            const float4* qs = (const float4*)(ze + (size_t)row * DDIM + d0);
            float4 a = qs[0], b = qs[1];
            float f[8] = {a.x,a.y,a.z,a.w,b.x,b.y,b.z,b.w};
            #pragma unroll
            for (int j = 0; j < 8; ++j) qh[m][kb].h[j] = (_Float16)f[j];
        }
    }
    // (2) cn -> LDS
    s_cn[tid]       = ((const float*)(ws + WS_CN))[tid];
    s_cn[tid + 256] = ((const float*)(ws + WS_CN))[tid + 256];

    // (3) issue T0 -> B0, T1 -> B1 (2 gloads per wave per tile)
    #pragma unroll
    for (int b = 0; b < 2; ++b)
        #pragma unroll
        for (int j = 0; j < 2; ++j)
            gload16(fragg + b * 8192 + j * 4096 + wave * 1024 + lane * 16,
                    (char*)s_frag[b] + j * 4096 + wave * 1024);

    unsigned b2[2][4], s2[2][4];
    #pragma unroll
    for (int m = 0; m < 2; ++m)
        #pragma unroll
        for (int r = 0; r < 4; ++r) { b2[m][r] = 0xFFFFFFFFu; s2[m][r] = 0xFFFFFFFFu; }

    // pre-loop fence: T0 landed (T1 stays in flight), cn ds_writes visible
    asm volatile("s_waitcnt vmcnt(2) lgkmcnt(0)" ::: "memory");
    __builtin_amdgcn_s_barrier();
    asm volatile("" ::: "memory");
    __builtin_amdgcn_sched_barrier(0);

    #pragma unroll
    for (int t = 0; t < 8; ++t) {
        if (t == 7)      { asm volatile("s_waitcnt vmcnt(0)" ::: "memory"); }
        else if (t >= 1) { asm volatile("s_waitcnt vmcnt(2)" ::: "memory"); }
        if (t >= 1) {
            __builtin_amdgcn_s_barrier();   // arrival-only: no vmcnt drain
            asm volatile("" ::: "memory");
            __builtin_amdgcn_sched_barrier(0);
        }
        if (t + 2 < 8) {                    // prefetch tile t+2 into ring
            const char* src = fragg + (size_t)(t + 2) * 8192;
            char* dst = (char*)s_frag[(t + 2) % 3];
            #pragma unroll
            for (int j = 0; j < 2; ++j)
                gload16(src + j * 4096 + wave * 1024 + lane * 16,
                        dst + j * 4096 + wave * 1024);
        }
        const f16x8* fb = s_frag[t % 3];
        f16x8 bh[4][2];                     // whole-tile preload: 8 ds_read_b128
        #pragma unroll
        for (int sub = 0; sub < 4; ++sub) {
            bh[sub][0] = fb[(sub * 2 + 0) * 64 + lane];
            bh[sub][1] = fb[(sub * 2 + 1) * 64 + lane];
        }
        #pragma unroll
        for (int sub = 0; sub < 4; ++sub) {
            f32x4 a0 = {0,0,0,0}, a1 = {0,0,0,0};
            a0 = __builtin_amdgcn_mfma_f32_16x16x32_f16(qh[0][0].v, bh[sub][0], a0, 0, 0, 0);
            a0 = __builtin_amdgcn_mfma_f32_16x16x32_f16(qh[0][1].v, bh[sub][1], a0, 0, 0, 0);
            a1 = __builtin_amdgcn_mfma_f32_16x16x32_f16(qh[1][0].v, bh[sub][0], a1, 0, 0, 0);
            a1 = __builtin_amdgcn_mfma_f32_16x16x32_f16(qh[1][1].v, bh[sub][1], a1, 0, 0, 0);

            unsigned code = (unsigned)(t * 64 + sub * 16) + (unsigned)(lane & 15);
            float cnv = s_cn[t * 64 + sub * 16 + (lane & 15)];
            #pragma unroll
            for (int r = 0; r < 4; ++r) {
                float d0 = fmaf(a0[r], -2.0f, cnv);
                unsigned u0 = (__float_as_uint(d0) & 0xFFFFFE00u) | code;
                s2[0][r] = umed3(b2[0][r], s2[0][r], u0);
                b2[0][r] = min(b2[0][r], u0);
                float d1 = fmaf(a1[r], -2.0f, cnv);
                unsigned u1 = (__float_as_uint(d1) & 0xFFFFFE00u) | code;
                s2[1][r] = umed3(b2[1][r], s2[1][r], u1);
                b2[1][r] = min(b2[1][r], u1);
            }
        }
    }

    // ---- cross-lane top-2 merge + ballot flag collection (wave-uniform) ----
    unsigned rowmask = 0;
    #pragma unroll
    for (int m = 0; m < 2; ++m) {
        #pragma unroll
        for (int r = 0; r < 4; ++r) {
            unsigned b = b2[m][r], s = s2[m][r];
            #pragma unroll
            for (int mask = 1; mask < 16; mask <<= 1) {
                unsigned ob = __shfl_xor((int)b, mask);
                unsigned os = __shfl_xor((int)s, mask);
                s = min(min(s, os), max(b, ob));
                b = min(b, ob);
            }
            bool flag = false;
            if ((lane & 15) == 0) {
                int lrow = m * 16 + quad * 4 + r;
                s_bidx[wave][lrow] = (int)(b & 511u);
                float fb_ = __uint_as_float(b & 0xFFFFFE00u);
                float fs_ = __uint_as_float(s & 0xFFFFFE00u);
                flag = (fs_ - fb_ <= DELTA);
            }
            unsigned long long bal = __ballot(flag);   // bits at 0/16/32/48
            rowmask |= ((unsigned)( bal        & 1ull) << (m * 16 + 0  + r))
                     | ((unsigned)((bal >> 16) & 1ull) << (m * 16 + 4  + r))
                     | ((unsigned)((bal >> 32) & 1ull) << (m * 16 + 8  + r))
                     | ((unsigned)((bal >> 48) & 1ull) << (m * 16 + 12 + r));
        }
    }

    // ---- per-wave fp64 exact refine (wave-uniform rowmask loop) ----
    const float*  cbT  = (const float*)(ws + WS_CBT);
    const double* cn64 = (const double*)(ws + WS_CN64);
    while (rowmask) {
        int lrow = __builtin_ctz(rowmask);
        rowmask &= rowmask - 1;
        int q = qb_wave + lrow;
        float qv = ze[(size_t)q * DDIM + lane];          // lane d holds q[d]
        double acc[8] = {0,0,0,0,0,0,0,0};               // codes lane*8+j
        #pragma unroll 8
        for (int d = 0; d < DDIM; ++d) {
            double qd = (double)__shfl(qv, d);
            const float4* c4 = (const float4*)(cbT + d * KCB + lane * 8);
            float4 x = c4[0], y = c4[1];
            acc[0] = fma((double)x.x, qd, acc[0]);
            acc[1] = fma((double)x.y, qd, acc[1]);
            acc[2] = fma((double)x.z, qd, acc[2]);
            acc[3] = fma((double)x.w, qd, acc[3]);
            acc[4] = fma((double)y.x, qd, acc[4]);
            acc[5] = fma((double)y.y, qd, acc[5]);
            acc[6] = fma((double)y.z, qd, acc[6]);
            acc[7] = fma((double)y.w, qd, acc[7]);
        }
        double v = DBL_MAX; int ki = 0;
        #pragma unroll
        for (int j = 0; j < 8; ++j) {                    // j asc -> smaller code wins ties
            int k = lane * 8 + j;
            double dj = fma(-2.0, acc[j], cn64[k]);      // d' - ||q||^2
            if (dj < v) { v = dj; ki = k; }
        }
        #pragma unroll
        for (int off = 1; off < 64; off <<= 1) {
            double ov = __shfl_xor(v, off);
            int    oi = __shfl_xor(ki, off);
            if (ov < v || (ov == v && oi < ki)) { v = ov; ki = oi; }
        }
        if (lane == 0) s_bidx[wave][lrow] = ki;
    }

    // ---- per-wave output: direct gather cb[bidx] -> out ----
    const float4* cb4 = (const float4*)cb;
    float4* o4 = (float4*)out + (size_t)qb_wave * 16;
    #pragma unroll
    for (int i = 0; i < 8; ++i) {
        int cc  = i * 64 + lane;            // 0..511
        int row = cc >> 4;                  // 0..31
        int sg  = cc & 15;
        int bi  = s_bidx[wave][row];
        o4[(size_t)row * 16 + sg] = cb4[(size_t)bi * 16 + sg];
    }
}

extern "C" void kernel_launch(void* const* d_in, const int* in_sizes, int n_in,
                              void* d_out, int out_size, void* d_ws, size_t ws_size,
                              hipStream_t stream) {
    const float* ze = (const float*)d_in[0];
    const float* cb = (const float*)d_in[1];
    float* out = (float*)d_out;
    char* ws = (char*)d_ws;

    const int nq = in_sizes[0] / DDIM;                 // 524288
    k_pre<<<64, 256, 0, stream>>>(cb, ws);
    k1<<<nq / 128, 256, 0, stream>>>(ze, cb, out, ws);
}